// Round 18
// baseline (202.662 us; speedup 1.0000x reference)
//
#include <hip/hip_runtime.h>
#include <math.h>

#define B_ 16
#define L_ 256
#define D_ 64

#define CHUNK 16                    // 256 blocks = 1/CU
#define WARM  5                     // R13-proven minimal
#define NCH   (L_ / CHUNK)

#define PITCH 64                    // 16 quads/slot; phys quad = dq ^ swz(slot)
#define NSLOT 127                   // slot 0 = zeros; 1..64 = x rows 0..63; 65..126 = h rows 0..61
#define FBUF  (NSLOT * PITCH)       // 8128 floats
#define LDSZ  (2 * FBUF)            // 63.5 KB

__device__ __forceinline__ int swz(int s) { return (s + (s >> 1)) & 7; }

// fast tanh via v_exp_f32: overflow/NaN-safe, ~1e-7 rel error (thr 1e-2)
__device__ __forceinline__ float ftanh(float x) {
    float ax = fabsf(x);
    float e  = __builtin_amdgcn_exp2f(-2.8853900818f * ax);   // e^{-2ax}
    float r  = (1.0f - e) * __builtin_amdgcn_rcpf(1.0f + e);
    return copysignf(r, x);
}

// DPP wave shifts with zero boundary fill (bound_ctrl=1).
// Safe ONLY with fully-uniform exec (R11/R15 lesson).
__device__ __forceinline__ float dpp_shr1(float x) {
    int r = __builtin_amdgcn_update_dpp(0, __float_as_int(x), 0x138, 0xF, 0xF, true);
    return __int_as_float(r);
}
__device__ __forceinline__ float dpp_shl1(float x) {
    int r = __builtin_amdgcn_update_dpp(0, __float_as_int(x), 0x130, 0xF, 0xF, true);
    return __int_as_float(r);
}

// ---------------------------------------------------------------------------
// fused_layer v4 — R15 data scheme, HALF the waves (R17 lesson: step cost is
// invariant to LDS instr mix; this tests barrier/wave-count vs LDS-pipe).
// 256 threads; thread computes rows r (0..31) and r+32 (32..63, row 63
// clamped->62 and discarded). All x(t) + h(t-1) in one double-buffered
// XOR-swizzled LDS frame: slot 0 = zeros, slots 1..64 = x rows, 65..126 =
// h rows 0..61; row i reads slots 2i..2i+2. Total LDS wave-instrs per step
// identical to R15 (48 read + 32 write) — single-variable experiment.
// x staged by 2-deep register prefetch (4 float4/thread, rows tid>>2).
// WARM=5 warm-up makes chunk starts exact. Row 63 finished by scan63.
__global__ __launch_bounds__(256, 1) void fused_layer(
        const float* __restrict__ X, float* __restrict__ H,
        const float* __restrict__ Wl, const float* __restrict__ bl) {
    __shared__ float lds[LDSZ];

    const int tid    = threadIdx.x;
    const int b      = blockIdx.x >> 4;
    const int ch     = blockIdx.x & (NCH - 1);
    const int T0     = ch * CHUNK;
    const int tw     = (T0 >= WARM) ? (T0 - WARM) : 0;
    const int tend   = T0 + CHUNK;
    const int btbase = b * L_;

    const int l8  = tid & 7;
    const int q0  = l8 << 1;
    const int c0  = l8 << 3;
    const int r1  = tid >> 3;                          // 0..31
    const int r2  = r1 + 32;                           // 32..63
    const int r2c = (r2 < 63) ? r2 : 62;               // clamped read row

    // x staging: thread stages row sr = tid>>2, data quads qs..qs+3
    const int sr  = tid >> 2;
    const int qs  = (tid & 3) << 2;
    const int sxs = sr + 1;
    const int vxs = swz(sxs);
    int xw[4];
#pragma unroll
    for (int k = 0; k < 4; ++k)
        xw[k] = sxs * PITCH + (((qs + k) ^ vxs) << 2);
    const int xsrc = (sr << 6) + (qs << 2);            // float offset in frame

    // read offsets: row i reads slots 2i..2i+2
    int roA0[3], roA1[3], roB0[3], roB1[3];
#pragma unroll
    for (int ki = 0; ki < 3; ++ki) {
        int s = 2 * r1 + ki;
        int v = swz(s);
        roA0[ki] = s * PITCH + ((q0 ^ v) << 2);
        roA1[ki] = s * PITCH + (((q0 + 1) ^ v) << 2);
        s = 2 * r2c + ki;
        v = swz(s);
        roB0[ki] = s * PITCH + ((q0 ^ v) << 2);
        roB1[ki] = s * PITCH + (((q0 + 1) ^ v) << 2);
    }
    // h write offsets (slot 65+i)
    const int shA = 65 + r1, vA = swz(shA);
    const int hwA0 = shA * PITCH + ((q0 ^ vA) << 2);
    const int hwA1 = shA * PITCH + (((q0 + 1) ^ vA) << 2);
    const int shB = 65 + r2, vB = swz(shB);
    const int hwB0 = shB * PITCH + ((q0 ^ vB) << 2);
    const int hwB1 = shB * PITCH + (((q0 + 1) ^ vB) << 2);

    const bool le0 = (l8 == 0);
    const bool le7 = (l8 == 7);

    float w[9];
#pragma unroll
    for (int k = 0; k < 9; ++k) w[k] = Wl[k];
    const float bias = bl[0];
    const float4 z4 = make_float4(0.f, 0.f, 0.f, 0.f);

    for (int k = tid; k < LDSZ / 4; k += 256)
        reinterpret_cast<float4*>(lds)[k] = z4;        // slot 0 + h(-1)=0
    __syncthreads();

    float* cur = lds;
    float* nxt = lds + FBUF;

    // stage x(tw) into cur
    {
        const float* xf = X + ((size_t)(btbase + tw) << 12) + xsrc;
#pragma unroll
        for (int k = 0; k < 4; ++k)
            *reinterpret_cast<float4*>(cur + xw[k]) =
                *reinterpret_cast<const float4*>(xf + (k << 2));
    }
    // register prefetch x(tw+1)
    float4 pa[4];
    {
        const int t1 = (tw + 1 < L_) ? tw + 1 : L_ - 1;
        const float* xf = X + ((size_t)(btbase + t1) << 12) + xsrc;
#pragma unroll
        for (int k = 0; k < 4; ++k)
            pa[k] = *reinterpret_cast<const float4*>(xf + (k << 2));
    }
    __syncthreads();

    for (int t = tw; t < tend; ++t) {
        // issue x(t+2) loads — 2 steps deep, off the serial chain
        float4 na[4];
        {
            const int t2 = (t + 2 < L_) ? t + 2 : L_ - 1;
            const float* xf = X + ((size_t)(btbase + t2) << 12) + xsrc;
#pragma unroll
            for (int k = 0; k < 4; ++k)
                na[k] = *reinterpret_cast<const float4*>(xf + (k << 2));
        }

        // ---- row r1 (uniform exec) ----
        float oA[8];
        {
            float u0[8], u1[8], u2[8];
#pragma unroll
            for (int k = 0; k < 8; ++k) { u0[k] = 0.f; u1[k] = bias; u2[k] = 0.f; }
#pragma unroll
            for (int ki = 0; ki < 3; ++ki) {
                const float4 o0 = *reinterpret_cast<const float4*>(cur + roA0[ki]);
                const float4 o1 = *reinterpret_cast<const float4*>(cur + roA1[ki]);
                const float g[8] = {o0.x,o0.y,o0.z,o0.w, o1.x,o1.y,o1.z,o1.w};
                const float wa = w[ki*3], wb = w[ki*3+1], wc = w[ki*3+2];
#pragma unroll
                for (int k = 0; k < 8; ++k) {
                    u0[k] = fmaf(wa, g[k], u0[k]);
                    u1[k] = fmaf(wb, g[k], u1[k]);
                    u2[k] = fmaf(wc, g[k], u2[k]);
                }
            }
            const float eLr = dpp_shr1(u0[7]);
            const float eRr = dpp_shl1(u2[0]);
            const float eL  = le0 ? 0.f : eLr;
            const float eR  = le7 ? 0.f : eRr;
            oA[0] = ftanh(eL + u1[0] + u2[1]);
#pragma unroll
            for (int k = 1; k < 7; ++k)
                oA[k] = ftanh(u0[k-1] + u1[k] + u2[k+1]);
            oA[7] = ftanh(u0[6] + u1[7] + eR);
        }
        // ---- row r2 (uniform exec) ----
        float oB[8];
        {
            float u0[8], u1[8], u2[8];
#pragma unroll
            for (int k = 0; k < 8; ++k) { u0[k] = 0.f; u1[k] = bias; u2[k] = 0.f; }
#pragma unroll
            for (int ki = 0; ki < 3; ++ki) {
                const float4 o0 = *reinterpret_cast<const float4*>(cur + roB0[ki]);
                const float4 o1 = *reinterpret_cast<const float4*>(cur + roB1[ki]);
                const float g[8] = {o0.x,o0.y,o0.z,o0.w, o1.x,o1.y,o1.z,o1.w};
                const float wa = w[ki*3], wb = w[ki*3+1], wc = w[ki*3+2];
#pragma unroll
                for (int k = 0; k < 8; ++k) {
                    u0[k] = fmaf(wa, g[k], u0[k]);
                    u1[k] = fmaf(wb, g[k], u1[k]);
                    u2[k] = fmaf(wc, g[k], u2[k]);
                }
            }
            const float eLr = dpp_shr1(u0[7]);
            const float eRr = dpp_shl1(u2[0]);
            const float eL  = le0 ? 0.f : eLr;
            const float eR  = le7 ? 0.f : eRr;
            oB[0] = ftanh(eL + u1[0] + u2[1]);
#pragma unroll
            for (int k = 1; k < 7; ++k)
                oB[k] = ftanh(u0[k-1] + u1[k] + u2[k+1]);
            oB[7] = ftanh(u0[6] + u1[7] + eR);
        }

        // ---- predicated stores (after all DPP) ----
        if (t >= T0) {
            float* gd = H + (((size_t)(btbase + t)) << 12) + (r1 << 6) + c0;
            *reinterpret_cast<float4*>(gd)     = make_float4(oA[0],oA[1],oA[2],oA[3]);
            *reinterpret_cast<float4*>(gd + 4) = make_float4(oA[4],oA[5],oA[6],oA[7]);
            if (r2 < 63) {
                float* gd2 = H + (((size_t)(btbase + t)) << 12) + (r2 << 6) + c0;
                *reinterpret_cast<float4*>(gd2)     = make_float4(oB[0],oB[1],oB[2],oB[3]);
                *reinterpret_cast<float4*>(gd2 + 4) = make_float4(oB[4],oB[5],oB[6],oB[7]);
            }
        }
        {   // h rows for next step
            *reinterpret_cast<float4*>(nxt + hwA0) = make_float4(oA[0],oA[1],oA[2],oA[3]);
            *reinterpret_cast<float4*>(nxt + hwA1) = make_float4(oA[4],oA[5],oA[6],oA[7]);
        }
        if (r2 <= 61) {
            *reinterpret_cast<float4*>(nxt + hwB0) = make_float4(oB[0],oB[1],oB[2],oB[3]);
            *reinterpret_cast<float4*>(nxt + hwB1) = make_float4(oB[4],oB[5],oB[6],oB[7]);
        }
        {   // commit x(t+1) into nxt
#pragma unroll
            for (int k = 0; k < 4; ++k)
                *reinterpret_cast<float4*>(nxt + xw[k]) = pa[k];
        }
        __syncthreads();
#pragma unroll
        for (int k = 0; k < 4; ++k) pa[k] = na[k];
        float* tmp = cur; cur = nxt; nxt = tmp;
    }
}

// ---------------------------------------------------------------------------
// Sequential scan for row 63 (reads rows 61/62 from global, written above).
#define SDEPTH 16
__global__ void scan63(float* __restrict__ dst,
                       const float* __restrict__ src,
                       const float* __restrict__ Wl,
                       const float* __restrict__ bl) {
    const int b = blockIdx.x;
    const int j = threadIdx.x;                         // 0..63, one wave
    float w[9];
#pragma unroll
    for (int k = 0; k < 9; ++k) w[k] = Wl[k];
    const float bias = bl[0];

    const size_t ST = (size_t)D_ * D_;
    const float* s61 = src + (size_t)b * L_ * ST + 61 * 64 + j;
    const float* s62 = src + (size_t)b * L_ * ST + 62 * 64 + j;
    float*       d63 = dst + (size_t)b * L_ * ST + 63 * 64 + j;

    float s = ftanh(bias);                             // t=0: h_{-1}=0
    d63[0] = s;

    float p61[SDEPTH], p62[SDEPTH];
#pragma unroll
    for (int u = 0; u < SDEPTH; ++u) {
        p61[u] = s61[(size_t)u * ST];
        p62[u] = s62[(size_t)u * ST];
    }

    for (int t0 = 1; t0 < 256; t0 += SDEPTH) {
#pragma unroll
        for (int u = 0; u < SDEPTH; ++u) {
            const int t = t0 + u;
            if (t > 255) break;
            const float r61 = p61[u], r62 = p62[u];
            int tp = t + SDEPTH - 1;
            if (tp > 255) tp = 255;
            p61[u] = s61[(size_t)tp * ST];
            p62[u] = s62[(size_t)tp * ST];
            float l1 = dpp_shr1(r61), q1 = dpp_shl1(r61);
            float l2 = dpp_shr1(r62), q2 = dpp_shl1(r62);
            float p = bias;
            p = fmaf(w[0], l1, p); p = fmaf(w[1], r61, p); p = fmaf(w[2], q1, p);
            p = fmaf(w[3], l2, p); p = fmaf(w[4], r62, p); p = fmaf(w[5], q2, p);
            float ls = dpp_shr1(s), rs = dpp_shl1(s);
            float z = fmaf(w[6], ls, fmaf(w[7], s, fmaf(w[8], rs, p)));
            s = ftanh(z);
            d63[(size_t)t * ST] = s;
        }
    }
}

extern "C" void kernel_launch(void* const* d_in, const int* in_sizes, int n_in,
                              void* d_out, int out_size, void* d_ws, size_t ws_size,
                              hipStream_t stream) {
    const float* x    = (const float*)d_in[0];   // (B,L,D,D)
    const float* W    = (const float*)d_in[1];   // (2,1,1,3,3)
    const float* bias = (const float*)d_in[2];   // (2,)
    float* out = (float*)d_out;
    float* h1  = (float*)d_ws;

    for (int l = 0; l < 2; ++l) {
        const float* X  = (l == 0) ? x  : h1;
        float*       H  = (l == 0) ? h1 : out;
        fused_layer<<<B_ * NCH, 256, 0, stream>>>(X, H, W + l * 9, bias + l);
        scan63<<<B_, 64, 0, stream>>>(H, H, W + l * 9, bias + l);
    }
}

// Round 19
// 112.014 us; speedup vs baseline: 1.8093x; 1.8093x over previous
//
#include <hip/hip_runtime.h>
#include <math.h>

#define B_ 16
#define L_ 256
#define D_ 64

#define CHUNK 16                    // 256 blocks = 1/CU
#define WARM  5                     // R13-proven minimal
#define NCH   (L_ / CHUNK)
#define NTH   1024                  // 16 waves (R18: wall ∝ per-wave chain; more waves, less chain)

#define PITCH 64                    // 16 quads/slot; phys quad = dq ^ swz(slot)
#define NSLOT 127                   // slot 0 = zeros; 1..64 = x rows 0..63; 65..126 = h rows 0..61
#define FBUF  (NSLOT * PITCH)       // 8128 floats
#define LDSZ  (2 * FBUF)            // 63.5 KB

__device__ __forceinline__ int swz(int s) { return (s + (s >> 1)) & 7; }

// fast tanh via v_exp_f32: overflow/NaN-safe, ~1e-7 rel error (thr 1e-2)
__device__ __forceinline__ float ftanh(float x) {
    float ax = fabsf(x);
    float e  = __builtin_amdgcn_exp2f(-2.8853900818f * ax);   // e^{-2ax}
    float r  = (1.0f - e) * __builtin_amdgcn_rcpf(1.0f + e);
    return copysignf(r, x);
}

// DPP wave shifts with zero boundary fill (bound_ctrl=1).
// Safe ONLY with fully-uniform exec (R11/R15 lesson).
__device__ __forceinline__ float dpp_shr1(float x) {
    int r = __builtin_amdgcn_update_dpp(0, __float_as_int(x), 0x138, 0xF, 0xF, true);
    return __int_as_float(r);
}
__device__ __forceinline__ float dpp_shl1(float x) {
    int r = __builtin_amdgcn_update_dpp(0, __float_as_int(x), 0x130, 0xF, 0xF, true);
    return __int_as_float(r);
}

// ---------------------------------------------------------------------------
// fused_layer v5 — R15 data scheme, 16 waves, 4 cols/thread (half the
// per-wave chain of R15; R18 proved wall ∝ per-wave serial chain).
// Row r = tid>>4, cols c0 = (tid&15)<<2. Per tap slot each thread reads ONE
// aligned quad (ds_read_b128); cross-column edges via u0/u1/u2 decompose +
// DPP under uniform exec, masked at l16==0/15 (column pads). Slot s holds
// concat row s-1 (slot 0 zeros; 1..64 x rows; 65..126 h rows 0..61); data
// quad dq at phys dq^swz(s). Row-63 lanes clamp reads to row 62 (slot 128
// would overflow) and discard results. x staged 1 float4/thread, 2-deep
// register prefetch. WARM=5 makes chunk starts exact. Row 63 -> scan63.
__global__ __launch_bounds__(NTH, 1) void fused_layer(
        const float* __restrict__ X, float* __restrict__ H,
        const float* __restrict__ Wl, const float* __restrict__ bl) {
    __shared__ float lds[LDSZ];

    const int tid    = threadIdx.x;
    const int b      = blockIdx.x >> 4;
    const int ch     = blockIdx.x & (NCH - 1);
    const int T0     = ch * CHUNK;
    const int tw     = (T0 >= WARM) ? (T0 - WARM) : 0;
    const int tend   = T0 + CHUNK;
    const int btbase = b * L_;

    const int r    = tid >> 4;                         // row 0..63
    const int l16  = tid & 15;
    const int q0   = l16;                              // own data quad
    const int c0   = l16 << 2;
    const int rc   = (r < 63) ? r : 62;                // clamped read row

    // x staging: thread stages quad l16 of x row r -> slot r+1
    const int sxs = r + 1;
    const int xw  = sxs * PITCH + ((q0 ^ swz(sxs)) << 2);
    // reads: slots 2rc..2rc+2, own quad
    int ro[3];
#pragma unroll
    for (int ki = 0; ki < 3; ++ki) {
        const int s = 2 * rc + ki;
        ro[ki] = s * PITCH + ((q0 ^ swz(s)) << 2);
    }
    // h write: slot 65+r (used when r<=61)
    const int shh = 65 + r;
    const int hw  = shh * PITCH + ((q0 ^ swz(shh)) << 2);

    const bool le0  = (l16 == 0);
    const bool le15 = (l16 == 15);

    float w[9];
#pragma unroll
    for (int k = 0; k < 9; ++k) w[k] = Wl[k];
    const float bias = bl[0];
    const float4 z4 = make_float4(0.f, 0.f, 0.f, 0.f);

    for (int k = tid; k < LDSZ / 4; k += NTH)
        reinterpret_cast<float4*>(lds)[k] = z4;        // slot 0 + h(-1)=0
    __syncthreads();

    float* cur = lds;
    float* nxt = lds + FBUF;

    // stage x(tw) into cur; source offset = (r<<6)+(l16<<2) == tid<<2
    {
        const float* xf = X + ((size_t)(btbase + tw) << 12) + (tid << 2);
        *reinterpret_cast<float4*>(cur + xw) = *reinterpret_cast<const float4*>(xf);
    }
    // register prefetch x(tw+1)
    float4 px;
    {
        const int t1 = (tw + 1 < L_) ? tw + 1 : L_ - 1;
        const float* xf = X + ((size_t)(btbase + t1) << 12) + (tid << 2);
        px = *reinterpret_cast<const float4*>(xf);
    }
    __syncthreads();

    for (int t = tw; t < tend; ++t) {
        // issue x(t+2) load — 2 steps deep, off the serial chain
        float4 nx;
        {
            const int t2 = (t + 2 < L_) ? t + 2 : L_ - 1;
            const float* xf = X + ((size_t)(btbase + t2) << 12) + (tid << 2);
            nx = *reinterpret_cast<const float4*>(xf);
        }

        // ---- uniform-exec compute: 3 reads, u decompose, DPP edges ----
        float u0[4], u1[4], u2[4];
#pragma unroll
        for (int k = 0; k < 4; ++k) { u0[k] = 0.f; u1[k] = bias; u2[k] = 0.f; }
#pragma unroll
        for (int ki = 0; ki < 3; ++ki) {
            const float4 o4 = *reinterpret_cast<const float4*>(cur + ro[ki]);
            const float g[4] = {o4.x, o4.y, o4.z, o4.w};
            const float wa = w[ki*3], wb = w[ki*3+1], wc = w[ki*3+2];
#pragma unroll
            for (int k = 0; k < 4; ++k) {
                u0[k] = fmaf(wa, g[k], u0[k]);
                u1[k] = fmaf(wb, g[k], u1[k]);
                u2[k] = fmaf(wc, g[k], u2[k]);
            }
        }
        const float eLr = dpp_shr1(u0[3]);             // left lane's u0[3]
        const float eRr = dpp_shl1(u2[0]);             // right lane's u2[0]
        const float eL  = le0  ? 0.f : eLr;            // col c0-1 term
        const float eR  = le15 ? 0.f : eRr;            // col c0+4 term

        float o0 = ftanh(eL    + u1[0] + u2[1]);
        float o1 = ftanh(u0[0] + u1[1] + u2[2]);
        float o2 = ftanh(u0[1] + u1[2] + u2[3]);
        float o3 = ftanh(u0[2] + u1[3] + eR);

        // ---- predicated stores (after all DPP) ----
        if (r < 63 && t >= T0) {
            float* gd = H + (((size_t)(btbase + t)) << 12) + (r << 6) + c0;
            *reinterpret_cast<float4*>(gd) = make_float4(o0, o1, o2, o3);
        }
        if (r <= 61) {                                 // h row for next step
            *reinterpret_cast<float4*>(nxt + hw) = make_float4(o0, o1, o2, o3);
        }
        {   // commit x(t+1) into nxt
            *reinterpret_cast<float4*>(nxt + xw) = px;
        }
        __syncthreads();
        px = nx;
        float* tmp = cur; cur = nxt; nxt = tmp;
    }
}

// ---------------------------------------------------------------------------
// Sequential scan for row 63 (reads rows 61/62 from global, written above).
#define SDEPTH 16
__global__ void scan63(float* __restrict__ dst,
                       const float* __restrict__ src,
                       const float* __restrict__ Wl,
                       const float* __restrict__ bl) {
    const int b = blockIdx.x;
    const int j = threadIdx.x;                         // 0..63, one wave
    float w[9];
#pragma unroll
    for (int k = 0; k < 9; ++k) w[k] = Wl[k];
    const float bias = bl[0];

    const size_t ST = (size_t)D_ * D_;
    const float* s61 = src + (size_t)b * L_ * ST + 61 * 64 + j;
    const float* s62 = src + (size_t)b * L_ * ST + 62 * 64 + j;
    float*       d63 = dst + (size_t)b * L_ * ST + 63 * 64 + j;

    float s = ftanh(bias);                             // t=0: h_{-1}=0
    d63[0] = s;

    float p61[SDEPTH], p62[SDEPTH];
#pragma unroll
    for (int u = 0; u < SDEPTH; ++u) {
        p61[u] = s61[(size_t)u * ST];
        p62[u] = s62[(size_t)u * ST];
    }

    for (int t0 = 1; t0 < 256; t0 += SDEPTH) {
#pragma unroll
        for (int u = 0; u < SDEPTH; ++u) {
            const int t = t0 + u;
            if (t > 255) break;
            const float r61 = p61[u], r62 = p62[u];
            int tp = t + SDEPTH - 1;
            if (tp > 255) tp = 255;
            p61[u] = s61[(size_t)tp * ST];
            p62[u] = s62[(size_t)tp * ST];
            float l1 = dpp_shr1(r61), q1 = dpp_shl1(r61);
            float l2 = dpp_shr1(r62), q2 = dpp_shl1(r62);
            float p = bias;
            p = fmaf(w[0], l1, p); p = fmaf(w[1], r61, p); p = fmaf(w[2], q1, p);
            p = fmaf(w[3], l2, p); p = fmaf(w[4], r62, p); p = fmaf(w[5], q2, p);
            float ls = dpp_shr1(s), rs = dpp_shl1(s);
            float z = fmaf(w[6], ls, fmaf(w[7], s, fmaf(w[8], rs, p)));
            s = ftanh(z);
            d63[(size_t)t * ST] = s;
        }
    }
}

extern "C" void kernel_launch(void* const* d_in, const int* in_sizes, int n_in,
                              void* d_out, int out_size, void* d_ws, size_t ws_size,
                              hipStream_t stream) {
    const float* x    = (const float*)d_in[0];   // (B,L,D,D)
    const float* W    = (const float*)d_in[1];   // (2,1,1,3,3)
    const float* bias = (const float*)d_in[2];   // (2,)
    float* out = (float*)d_out;
    float* h1  = (float*)d_ws;

    for (int l = 0; l < 2; ++l) {
        const float* X  = (l == 0) ? x  : h1;
        float*       H  = (l == 0) ? h1 : out;
        fused_layer<<<B_ * NCH, NTH, 0, stream>>>(X, H, W + l * 9, bias + l);
        scan63<<<B_, 64, 0, stream>>>(H, H, W + l * 9, bias + l);
    }
}

// Round 20
// 111.992 us; speedup vs baseline: 1.8096x; 1.0002x over previous
//
#include <hip/hip_runtime.h>
#include <math.h>

#define B_ 16
#define L_ 256
#define D_ 64

#define CHUNK 16                    // 256 blocks = 1/CU
#define WARM  5                     // R13-proven minimal
#define NCH   (L_ / CHUNK)
#define NTH   1024                  // 16 waves (R19: >=8 waves = plateau; keep 16)

#define PITCH 64                    // 16 quads/slot; phys quad = dq ^ swz(slot)
#define NSLOT 127                   // slot 0 = zeros; 1..64 = x rows 0..63; 65..126 = h rows 0..61
#define FBUF  (NSLOT * PITCH)       // 8128 floats
#define LDSZ  (2 * FBUF)            // 63.5 KB

__device__ __forceinline__ int swz(int s) { return (s + (s >> 1)) & 7; }

// fast tanh via v_exp_f32: overflow/NaN-safe, ~1e-7 rel error (thr 1e-2)
__device__ __forceinline__ float ftanh(float x) {
    float ax = fabsf(x);
    float e  = __builtin_amdgcn_exp2f(-2.8853900818f * ax);   // e^{-2ax}
    float r  = (1.0f - e) * __builtin_amdgcn_rcpf(1.0f + e);
    return copysignf(r, x);
}

// DPP wave shifts with zero boundary fill (bound_ctrl=1).
// Safe ONLY with fully-uniform exec (R11/R15 lesson).
__device__ __forceinline__ float dpp_shr1(float x) {
    int r = __builtin_amdgcn_update_dpp(0, __float_as_int(x), 0x138, 0xF, 0xF, true);
    return __int_as_float(r);
}
__device__ __forceinline__ float dpp_shl1(float x) {
    int r = __builtin_amdgcn_update_dpp(0, __float_as_int(x), 0x130, 0xF, 0xF, true);
    return __int_as_float(r);
}

// ---------------------------------------------------------------------------
// fused_layer v6 — R19 structure + RAW BARRIER (T4 lesson: __syncthreads
// lowers to s_waitcnt vmcnt(0) lgkmcnt(0) + s_barrier; the vmcnt(0) drains
// H-store acks AND the just-issued x(t+2) prefetch at EVERY step — the
// unaccounted ~2400 cyc/step stall. The barrier only needs LDS visibility,
// so wait lgkmcnt(0) only; compiler still inserts fine-grained vmcnt(N)
// before the ds_write of the prefetched x, one step later = fully landed).
// Row r = tid>>4, cols c0 = (tid&15)<<2. Slot s = concat row s-1; data quad
// dq at phys dq^swz(s). Row-63 lanes clamp reads to row 62 and discard.
// WARM=5 warm-up makes chunk starts exact. Row 63 -> scan63.
__global__ __launch_bounds__(NTH, 1) void fused_layer(
        const float* __restrict__ X, float* __restrict__ H,
        const float* __restrict__ Wl, const float* __restrict__ bl) {
    __shared__ float lds[LDSZ];

    const int tid    = threadIdx.x;
    const int b      = blockIdx.x >> 4;
    const int ch     = blockIdx.x & (NCH - 1);
    const int T0     = ch * CHUNK;
    const int tw     = (T0 >= WARM) ? (T0 - WARM) : 0;
    const int tend   = T0 + CHUNK;
    const int btbase = b * L_;

    const int r    = tid >> 4;                         // row 0..63
    const int l16  = tid & 15;
    const int q0   = l16;                              // own data quad
    const int c0   = l16 << 2;
    const int rc   = (r < 63) ? r : 62;                // clamped read row

    // x staging: thread stages quad l16 of x row r -> slot r+1
    const int sxs = r + 1;
    const int xw  = sxs * PITCH + ((q0 ^ swz(sxs)) << 2);
    // reads: slots 2rc..2rc+2, own quad
    int ro[3];
#pragma unroll
    for (int ki = 0; ki < 3; ++ki) {
        const int s = 2 * rc + ki;
        ro[ki] = s * PITCH + ((q0 ^ swz(s)) << 2);
    }
    // h write: slot 65+r (used when r<=61)
    const int shh = 65 + r;
    const int hw  = shh * PITCH + ((q0 ^ swz(shh)) << 2);

    const bool le0  = (l16 == 0);
    const bool le15 = (l16 == 15);

    float w[9];
#pragma unroll
    for (int k = 0; k < 9; ++k) w[k] = Wl[k];
    const float bias = bl[0];
    const float4 z4 = make_float4(0.f, 0.f, 0.f, 0.f);

    for (int k = tid; k < LDSZ / 4; k += NTH)
        reinterpret_cast<float4*>(lds)[k] = z4;        // slot 0 + h(-1)=0
    __syncthreads();

    float* cur = lds;
    float* nxt = lds + FBUF;

    // stage x(tw) into cur; source offset = (r<<6)+(l16<<2) == tid<<2
    {
        const float* xf = X + ((size_t)(btbase + tw) << 12) + (tid << 2);
        *reinterpret_cast<float4*>(cur + xw) = *reinterpret_cast<const float4*>(xf);
    }
    // register prefetch x(tw+1)
    float4 px;
    {
        const int t1 = (tw + 1 < L_) ? tw + 1 : L_ - 1;
        const float* xf = X + ((size_t)(btbase + t1) << 12) + (tid << 2);
        px = *reinterpret_cast<const float4*>(xf);
    }
    __syncthreads();

    for (int t = tw; t < tend; ++t) {
        // issue x(t+2) load — 2 steps deep; NOT drained at the raw barrier
        float4 nx;
        {
            const int t2 = (t + 2 < L_) ? t + 2 : L_ - 1;
            const float* xf = X + ((size_t)(btbase + t2) << 12) + (tid << 2);
            nx = *reinterpret_cast<const float4*>(xf);
        }

        // ---- uniform-exec compute: 3 reads, u decompose, DPP edges ----
        float u0[4], u1[4], u2[4];
#pragma unroll
        for (int k = 0; k < 4; ++k) { u0[k] = 0.f; u1[k] = bias; u2[k] = 0.f; }
#pragma unroll
        for (int ki = 0; ki < 3; ++ki) {
            const float4 o4 = *reinterpret_cast<const float4*>(cur + ro[ki]);
            const float g[4] = {o4.x, o4.y, o4.z, o4.w};
            const float wa = w[ki*3], wb = w[ki*3+1], wc = w[ki*3+2];
#pragma unroll
            for (int k = 0; k < 4; ++k) {
                u0[k] = fmaf(wa, g[k], u0[k]);
                u1[k] = fmaf(wb, g[k], u1[k]);
                u2[k] = fmaf(wc, g[k], u2[k]);
            }
        }
        const float eLr = dpp_shr1(u0[3]);             // left lane's u0[3]
        const float eRr = dpp_shl1(u2[0]);             // right lane's u2[0]
        const float eL  = le0  ? 0.f : eLr;            // col c0-1 term
        const float eR  = le15 ? 0.f : eRr;            // col c0+4 term

        float o0 = ftanh(eL    + u1[0] + u2[1]);
        float o1 = ftanh(u0[0] + u1[1] + u2[2]);
        float o2 = ftanh(u0[1] + u1[2] + u2[3]);
        float o3 = ftanh(u0[2] + u1[3] + eR);

        // ---- predicated stores (after all DPP) ----
        if (r < 63 && t >= T0) {                       // H store: ack NOT waited
            float* gd = H + (((size_t)(btbase + t)) << 12) + (r << 6) + c0;
            *reinterpret_cast<float4*>(gd) = make_float4(o0, o1, o2, o3);
        }
        if (r <= 61) {                                 // h row for next step
            *reinterpret_cast<float4*>(nxt + hw) = make_float4(o0, o1, o2, o3);
        }
        {   // commit x(t+1) into nxt (compiler adds fine-grained vmcnt for px)
            *reinterpret_cast<float4*>(nxt + xw) = px;
        }
        // raw barrier: wait LDS only — no vmcnt(0) drain (T4 pattern)
        asm volatile("s_waitcnt lgkmcnt(0)" ::: "memory");
        __builtin_amdgcn_s_barrier();
        px = nx;
        float* tmp = cur; cur = nxt; nxt = tmp;
    }
}

// ---------------------------------------------------------------------------
// Sequential scan for row 63 (reads rows 61/62 from global, written above).
#define SDEPTH 16
__global__ void scan63(float* __restrict__ dst,
                       const float* __restrict__ src,
                       const float* __restrict__ Wl,
                       const float* __restrict__ bl) {
    const int b = blockIdx.x;
    const int j = threadIdx.x;                         // 0..63, one wave
    float w[9];
#pragma unroll
    for (int k = 0; k < 9; ++k) w[k] = Wl[k];
    const float bias = bl[0];

    const size_t ST = (size_t)D_ * D_;
    const float* s61 = src + (size_t)b * L_ * ST + 61 * 64 + j;
    const float* s62 = src + (size_t)b * L_ * ST + 62 * 64 + j;
    float*       d63 = dst + (size_t)b * L_ * ST + 63 * 64 + j;

    float s = ftanh(bias);                             // t=0: h_{-1}=0
    d63[0] = s;

    float p61[SDEPTH], p62[SDEPTH];
#pragma unroll
    for (int u = 0; u < SDEPTH; ++u) {
        p61[u] = s61[(size_t)u * ST];
        p62[u] = s62[(size_t)u * ST];
    }

    for (int t0 = 1; t0 < 256; t0 += SDEPTH) {
#pragma unroll
        for (int u = 0; u < SDEPTH; ++u) {
            const int t = t0 + u;
            if (t > 255) break;
            const float r61 = p61[u], r62 = p62[u];
            int tp = t + SDEPTH - 1;
            if (tp > 255) tp = 255;
            p61[u] = s61[(size_t)tp * ST];
            p62[u] = s62[(size_t)tp * ST];
            float l1 = dpp_shr1(r61), q1 = dpp_shl1(r61);
            float l2 = dpp_shr1(r62), q2 = dpp_shl1(r62);
            float p = bias;
            p = fmaf(w[0], l1, p); p = fmaf(w[1], r61, p); p = fmaf(w[2], q1, p);
            p = fmaf(w[3], l2, p); p = fmaf(w[4], r62, p); p = fmaf(w[5], q2, p);
            float ls = dpp_shr1(s), rs = dpp_shl1(s);
            float z = fmaf(w[6], ls, fmaf(w[7], s, fmaf(w[8], rs, p)));
            s = ftanh(z);
            d63[(size_t)t * ST] = s;
        }
    }
}

extern "C" void kernel_launch(void* const* d_in, const int* in_sizes, int n_in,
                              void* d_out, int out_size, void* d_ws, size_t ws_size,
                              hipStream_t stream) {
    const float* x    = (const float*)d_in[0];   // (B,L,D,D)
    const float* W    = (const float*)d_in[1];   // (2,1,1,3,3)
    const float* bias = (const float*)d_in[2];   // (2,)
    float* out = (float*)d_out;
    float* h1  = (float*)d_ws;

    for (int l = 0; l < 2; ++l) {
        const float* X  = (l == 0) ? x  : h1;
        float*       H  = (l == 0) ? h1 : out;
        fused_layer<<<B_ * NCH, NTH, 0, stream>>>(X, H, W + l * 9, bias + l);
        scan63<<<B_, 64, 0, stream>>>(H, H, W + l * 9, bias + l);
    }
}

// Round 21
// 104.515 us; speedup vs baseline: 1.9391x; 1.0715x over previous
//
#include <hip/hip_runtime.h>
#include <math.h>

#define B_ 16
#define L_ 256
#define D_ 64

#define CHUNK 16                    // 256 blocks = 1/CU
#define WARM  5                     // rows 0..31 now ALWAYS exact (reg-sourced); level-k at tw+k
#define NCH   (L_ / CHUNK)
#define NTH   1024                  // 16 waves

#define PITCH 64                    // 16 quads/slot; phys quad = dq ^ swz(slot)
#define NSLOT 63                    // slot 0 = x(t) row 63; slot 1+j = h(t-1) row j (j=0..61)
#define FBUF  (NSLOT * PITCH)       // 4032 floats
#define LDSZ  (2 * FBUF)            // 8064 floats = 31.5 KB

__device__ __forceinline__ int swz(int s) { return (s + (s >> 1)) & 7; }

// fast tanh via v_exp_f32: overflow/NaN-safe, ~1e-7 rel error (thr 1e-2)
__device__ __forceinline__ float ftanh(float x) {
    float ax = fabsf(x);
    float e  = __builtin_amdgcn_exp2f(-2.8853900818f * ax);   // e^{-2ax}
    float r  = (1.0f - e) * __builtin_amdgcn_rcpf(1.0f + e);
    return copysignf(r, x);
}

// DPP wave shifts with zero boundary fill (bound_ctrl=1).
// Safe ONLY with fully-uniform exec (R11/R15 lesson).
__device__ __forceinline__ float dpp_shr1(float x) {
    int r = __builtin_amdgcn_update_dpp(0, __float_as_int(x), 0x138, 0xF, 0xF, true);
    return __int_as_float(r);
}
__device__ __forceinline__ float dpp_shl1(float x) {
    int r = __builtin_amdgcn_update_dpp(0, __float_as_int(x), 0x130, 0xF, 0xF, true);
    return __int_as_float(r);
}

// ---------------------------------------------------------------------------
// fused_layer v7 — 16 waves, 4 cols/thread, HALF the LDS traffic of v6:
// rows 0..31 (waves 0..7, wave-uniform) read their 3 x-window float4s from
// GLOBAL into registers (1-step prefetch) — zero LDS on that path. LDS keeps
// only h(t-1) rows 0..61 (slots 1..62) + x(t) row 63 (slot 0, staged by the
// row-63 lanes whose conv output is discarded). Row i>=32 reads slots
// 2i-64..2i-62. RAW barrier (lgkmcnt-only, R20-proven) keeps the prefetch
// loads in flight across steps — R17's regression was these loads being
// vmcnt(0)-drained by __syncthreads every step, not the global reads
// themselves. WARM=5 warm-up makes chunk starts exact. Row 63 -> scan63.
__global__ __launch_bounds__(NTH, 1) void fused_layer(
        const float* __restrict__ X, float* __restrict__ H,
        const float* __restrict__ Wl, const float* __restrict__ bl) {
    __shared__ float lds[LDSZ];

    const int tid    = threadIdx.x;
    const int b      = blockIdx.x >> 4;
    const int ch     = blockIdx.x & (NCH - 1);
    const int T0     = ch * CHUNK;
    const int tw     = (T0 >= WARM) ? (T0 - WARM) : 0;
    const int tend   = T0 + CHUNK;
    const int btbase = b * L_;

    const int r    = tid >> 4;                         // row 0..63
    const int l16  = tid & 15;
    const int q0   = l16;
    const int c0   = l16 << 2;
    const bool lvl0 = (r < 32);                        // wave-uniform (waves 0..7)
    const bool st63 = (r == 63);                       // x row-63 stagers
    const int  rc   = (r < 63) ? r : 62;               // clamped mid read row

    // mid reads: slots 2rc-64..2rc-62 (slot 0 = x63, 1+j = h row j)
    int ro[3];
#pragma unroll
    for (int ki = 0; ki < 3; ++ki) {
        const int s = 2 * rc - 64 + ki;                // 0..62
        const int sc = (s < 0) ? 0 : s;                // only hit when lvl0 (unused)
        ro[ki] = sc * PITCH + ((q0 ^ swz(sc)) << 2);
    }
    // h write: slot r+1 (used when r<=61)
    const int shh = r + 1;
    const int hw  = (shh <= 62 ? shh : 62) * PITCH + ((q0 ^ swz(shh <= 62 ? shh : 62)) << 2);
    // x63 stage write: slot 0 (swz(0)=0)
    const int xw  = q0 << 2;

    const bool le0  = (l16 == 0);
    const bool le15 = (l16 == 15);

    float w[9];
#pragma unroll
    for (int k = 0; k < 9; ++k) w[k] = Wl[k];
    const float bias = bl[0];
    const float4 z4 = make_float4(0.f, 0.f, 0.f, 0.f);

    for (int k = tid; k < LDSZ / 4; k += NTH)
        reinterpret_cast<float4*>(lds)[k] = z4;        // h(-1)=0 for chunk 0
    __syncthreads();

    float* cur = lds;
    float* nxt = lds + FBUF;

    // pre-loop: lvl0 loads x(tw) windows into cx; st63 stages x(tw) row 63
    float4 cx0 = z4, cx1 = z4, cx2 = z4;
    if (lvl0) {
        const float* xf = X + ((size_t)(btbase + tw) << 12);
        const int cr0 = 2 * r - 1;
        if (cr0 >= 0) cx0 = *reinterpret_cast<const float4*>(xf + (cr0 << 6) + c0);
        cx1 = *reinterpret_cast<const float4*>(xf + ((cr0 + 1) << 6) + c0);
        cx2 = *reinterpret_cast<const float4*>(xf + ((cr0 + 2) << 6) + c0);
    }
    float4 p63 = z4;
    if (st63) {
        const float* xf = X + ((size_t)(btbase + tw) << 12) + (63 << 6) + c0;
        *reinterpret_cast<float4*>(cur + xw) = *reinterpret_cast<const float4*>(xf);
        const int t1 = (tw + 1 < L_) ? tw + 1 : L_ - 1;
        p63 = *reinterpret_cast<const float4*>(
            X + ((size_t)(btbase + t1) << 12) + (63 << 6) + c0);
    }
    __syncthreads();

    for (int t = tw; t < tend; ++t) {
        // issue next-step loads (NOT drained at the raw barrier)
        float4 nx0 = z4, nx1 = z4, nx2 = z4, n63 = z4;
        if (lvl0) {
            const int tn = (t + 1 < L_) ? t + 1 : L_ - 1;
            const float* xf = X + ((size_t)(btbase + tn) << 12);
            const int cr0 = 2 * r - 1;
            if (cr0 >= 0) nx0 = *reinterpret_cast<const float4*>(xf + (cr0 << 6) + c0);
            nx1 = *reinterpret_cast<const float4*>(xf + ((cr0 + 1) << 6) + c0);
            nx2 = *reinterpret_cast<const float4*>(xf + ((cr0 + 2) << 6) + c0);
        }
        if (st63) {
            const int t2 = (t + 2 < L_) ? t + 2 : L_ - 1;
            n63 = *reinterpret_cast<const float4*>(
                X + ((size_t)(btbase + t2) << 12) + (63 << 6) + c0);
        }

        // ---- compute: g source is wave-uniform (regs vs LDS) ----
        float u0[4], u1[4], u2[4];
#pragma unroll
        for (int k = 0; k < 4; ++k) { u0[k] = 0.f; u1[k] = bias; u2[k] = 0.f; }
#pragma unroll
        for (int ki = 0; ki < 3; ++ki) {
            float g[4];
            if (lvl0) {
                const float4 o4 = (ki == 0) ? cx0 : (ki == 1) ? cx1 : cx2;
                g[0] = o4.x; g[1] = o4.y; g[2] = o4.z; g[3] = o4.w;
            } else {
                const float4 o4 = *reinterpret_cast<const float4*>(cur + ro[ki]);
                g[0] = o4.x; g[1] = o4.y; g[2] = o4.z; g[3] = o4.w;
            }
            const float wa = w[ki*3], wb = w[ki*3+1], wc = w[ki*3+2];
#pragma unroll
            for (int k = 0; k < 4; ++k) {
                u0[k] = fmaf(wa, g[k], u0[k]);
                u1[k] = fmaf(wb, g[k], u1[k]);
                u2[k] = fmaf(wc, g[k], u2[k]);
            }
        }
        // cross-lane edges — uniform exec; row-boundary lanes masked (col pads)
        const float eLr = dpp_shr1(u0[3]);
        const float eRr = dpp_shl1(u2[0]);
        const float eL  = le0  ? 0.f : eLr;
        const float eR  = le15 ? 0.f : eRr;

        const float o0 = ftanh(eL    + u1[0] + u2[1]);
        const float o1 = ftanh(u0[0] + u1[1] + u2[2]);
        const float o2 = ftanh(u0[1] + u1[2] + u2[3]);
        const float o3 = ftanh(u0[2] + u1[3] + eR);

        // ---- predicated stores (after all DPP) ----
        if (r < 63 && t >= T0) {
            float* gd = H + (((size_t)(btbase + t)) << 12) + (r << 6) + c0;
            *reinterpret_cast<float4*>(gd) = make_float4(o0, o1, o2, o3);
        }
        if (r <= 61) {                                 // h row for next step
            *reinterpret_cast<float4*>(nxt + hw) = make_float4(o0, o1, o2, o3);
        }
        if (st63) {                                    // x(t+1) row 63 -> slot 0
            *reinterpret_cast<float4*>(nxt + xw) = p63;
        }
        // raw barrier: LDS-visibility only (R20-proven pattern)
        asm volatile("s_waitcnt lgkmcnt(0)" ::: "memory");
        __builtin_amdgcn_s_barrier();
        cx0 = nx0; cx1 = nx1; cx2 = nx2; p63 = n63;
        float* tmp = cur; cur = nxt; nxt = tmp;
    }
}

// ---------------------------------------------------------------------------
// Sequential scan for row 63 (reads rows 61/62 from global, written above).
#define SDEPTH 16
__global__ void scan63(float* __restrict__ dst,
                       const float* __restrict__ src,
                       const float* __restrict__ Wl,
                       const float* __restrict__ bl) {
    const int b = blockIdx.x;
    const int j = threadIdx.x;                         // 0..63, one wave
    float w[9];
#pragma unroll
    for (int k = 0; k < 9; ++k) w[k] = Wl[k];
    const float bias = bl[0];

    const size_t ST = (size_t)D_ * D_;
    const float* s61 = src + (size_t)b * L_ * ST + 61 * 64 + j;
    const float* s62 = src + (size_t)b * L_ * ST + 62 * 64 + j;
    float*       d63 = dst + (size_t)b * L_ * ST + 63 * 64 + j;

    float s = ftanh(bias);                             // t=0: h_{-1}=0
    d63[0] = s;

    float p61[SDEPTH], p62[SDEPTH];
#pragma unroll
    for (int u = 0; u < SDEPTH; ++u) {
        p61[u] = s61[(size_t)u * ST];
        p62[u] = s62[(size_t)u * ST];
    }

    for (int t0 = 1; t0 < 256; t0 += SDEPTH) {
#pragma unroll
        for (int u = 0; u < SDEPTH; ++u) {
            const int t = t0 + u;
            if (t > 255) break;
            const float r61 = p61[u], r62 = p62[u];
            int tp = t + SDEPTH - 1;
            if (tp > 255) tp = 255;
            p61[u] = s61[(size_t)tp * ST];
            p62[u] = s62[(size_t)tp * ST];
            float l1 = dpp_shr1(r61), q1 = dpp_shl1(r61);
            float l2 = dpp_shr1(r62), q2 = dpp_shl1(r62);
            float p = bias;
            p = fmaf(w[0], l1, p); p = fmaf(w[1], r61, p); p = fmaf(w[2], q1, p);
            p = fmaf(w[3], l2, p); p = fmaf(w[4], r62, p); p = fmaf(w[5], q2, p);
            float ls = dpp_shr1(s), rs = dpp_shl1(s);
            float z = fmaf(w[6], ls, fmaf(w[7], s, fmaf(w[8], rs, p)));
            s = ftanh(z);
            d63[(size_t)t * ST] = s;
        }
    }
}

extern "C" void kernel_launch(void* const* d_in, const int* in_sizes, int n_in,
                              void* d_out, int out_size, void* d_ws, size_t ws_size,
                              hipStream_t stream) {
    const float* x    = (const float*)d_in[0];   // (B,L,D,D)
    const float* W    = (const float*)d_in[1];   // (2,1,1,3,3)
    const float* bias = (const float*)d_in[2];   // (2,)
    float* out = (float*)d_out;
    float* h1  = (float*)d_ws;

    for (int l = 0; l < 2; ++l) {
        const float* X  = (l == 0) ? x  : h1;
        float*       H  = (l == 0) ? h1 : out;
        fused_layer<<<B_ * NCH, NTH, 0, stream>>>(X, H, W + l * 9, bias + l);
        scan63<<<B_, 64, 0, stream>>>(H, H, W + l * 9, bias + l);
    }
}